// Round 3
// baseline (2800.462 us; speedup 1.0000x reference)
//
#include <hip/hip_runtime.h>
#include <hip/hip_cooperative_groups.h>
#include <math.h>

namespace cg = cooperative_groups;

// Problem constants: B=128, MAXLEN=20, E=H=512, V=32000
#define NB 128
#define NT 20
#define NH 512
#define NV 32000
#define NG 2048   // 4*H
#define NK 512    // E == H

typedef __attribute__((ext_vector_type(8))) short s8v;   // 8 x bf16 (4 VGPR)
typedef __attribute__((ext_vector_type(4))) float f4v;   // MFMA accumulator
union F4 { float4 v; float f[4]; };

__device__ __forceinline__ float sigmoidf_(float x) { return 1.0f / (1.0f + expf(-x)); }

__device__ __forceinline__ ushort f2bf(float f) {   // round-to-nearest-even
    union { float f; unsigned u; } x; x.f = f;
    unsigned r = x.u + 0x7fffu + ((x.u >> 16) & 1u);
    return (ushort)(r >> 16);
}

__device__ __forceinline__ void gload16(const void* g, void* l) {
    // async global->LDS, 16B/lane, dest = wave-uniform base + lane*16
    __builtin_amdgcn_global_load_lds((const __attribute__((address_space(1))) void*)g,
                                     (__attribute__((address_space(3))) void*)l, 16, 0, 0);
}

// ---------------------------------------------------------------------------
// prep: bias2048 = b_ih + b_hh; idx3[r] = Hs row for packed output row r
// (pack_padded order), padded with -1 up to mpad3.
// ---------------------------------------------------------------------------
__global__ __launch_bounds__(256) void prep_kernel(
    const int* __restrict__ lengths, const float* __restrict__ b_ih,
    const float* __restrict__ b_hh, float* __restrict__ bias,
    int* __restrict__ idx3, int mpad3)
{
    const int tid = threadIdx.x;
    for (int j = tid; j < NG; j += 256) bias[j] = b_ih[j] + b_hh[j];

    __shared__ unsigned long long s_mask[4];
    __shared__ int s_off;
    if (tid == 0) s_off = 0;
    const int len  = (tid < NB) ? lengths[tid] : 0;
    const int lane = tid & 63, wv = tid >> 6;
    __syncthreads();
    for (int t = 0; t < NT; ++t) {
        const bool flag = (len > t);
        unsigned long long bm = __ballot(flag ? 1 : 0);
        if (lane == 0) s_mask[wv] = bm;
        __syncthreads();
        int pos = s_off;
        for (int w = 0; w < wv; ++w) pos += __popcll(s_mask[w]);
        pos += __popcll(bm & ((1ull << lane) - 1ull));
        if (flag) idx3[pos] = t * NB + tid;
        __syncthreads();
        if (tid == 0) {
            int tot = 0;
            for (int w = 0; w < 4; ++w) tot += __popcll(s_mask[w]);
            s_off += tot;
        }
        __syncthreads();
    }
    for (int m = s_off + tid; m < mpad3; m += 256) idx3[m] = -1;
}

// ---------------------------------------------------------------------------
// xpack: Xpack[t*128+b][:] = bf16( t==0 ? features[b] : embed_w[cap[b][t-1]] )
// 2560 rows x 512; 64 threads/row, 8 elems/thread.
// ---------------------------------------------------------------------------
__global__ __launch_bounds__(256) void xpack_kernel(
    const float* __restrict__ features, const int* __restrict__ captions,
    const float* __restrict__ embed_w, ushort* __restrict__ Xpack)
{
    const int gid = blockIdx.x * 256 + threadIdx.x;  // 0..163839
    const int r = gid >> 6, cc = (gid & 63) << 3;
    const int t = r >> 7, b = r & 127;
    const float* src = (t == 0) ? (features + (size_t)b * NK)
                                : (embed_w + (size_t)captions[b * NT + t - 1] * NK);
    F4 v0, v1; v0.v = *(const float4*)(src + cc); v1.v = *(const float4*)(src + cc + 4);
    s8v o;
#pragma unroll
    for (int e = 0; e < 4; ++e) { o[e] = (short)f2bf(v0.f[e]); o[e + 4] = (short)f2bf(v1.f[e]); }
    *(s8v*)(Xpack + (size_t)r * NK + cc) = o;
}

// ---------------------------------------------------------------------------
// wconv: fp32 -> bf16, 8 elems/thread (n divisible by 8)
// ---------------------------------------------------------------------------
__global__ __launch_bounds__(256) void wconv_kernel(
    const float* __restrict__ in, ushort* __restrict__ outw, int n8)
{
    const int gid = blockIdx.x * 256 + threadIdx.x;
    if (gid >= n8) return;
    const int i = gid << 3;
    F4 v0, v1; v0.v = *(const float4*)(in + i); v1.v = *(const float4*)(in + i + 4);
    s8v o;
#pragma unroll
    for (int e = 0; e < 4; ++e) { o[e] = (short)f2bf(v0.f[e]); o[e + 4] = (short)f2bf(v1.f[e]); }
    *(s8v*)(outw + i) = o;
}

// ---------------------------------------------------------------------------
// gather: Apack[r][:] = bf16(Hs[idx3[r]][:]) or zeros for pad rows
// ---------------------------------------------------------------------------
__global__ __launch_bounds__(256) void gather_kernel(
    const float* __restrict__ Hs, const int* __restrict__ idx3,
    ushort* __restrict__ Apack)
{
    const int gid = blockIdx.x * 256 + threadIdx.x;
    const int r = gid >> 6, cc = (gid & 63) << 3;
    const int src = idx3[r];
    s8v o;
    if (src < 0) {
#pragma unroll
        for (int e = 0; e < 8; ++e) o[e] = 0;
    } else {
        const float* s = Hs + (size_t)src * NH + cc;
        F4 v0, v1; v0.v = *(const float4*)s; v1.v = *(const float4*)(s + 4);
#pragma unroll
        for (int e = 0; e < 4; ++e) { o[e] = (short)f2bf(v0.f[e]); o[e + 4] = (short)f2bf(v1.f[e]); }
    }
    *(s8v*)(Apack + (size_t)r * NK + cc) = o;
}

// ---------------------------------------------------------------------------
// bf16 MFMA GEMM: C[m][n] = sum_k A[m][k]*B[n][k] + bias[n]   (K = 512)
// 128x128 tile, BK=64, 4 waves (2x2 of 64x64), 16x16x32 MFMA, m97 structure:
// global_load_lds width-16 staging, XOR-swizzled LDS (both sides, rule #21).
// ---------------------------------------------------------------------------
__global__ __launch_bounds__(256, 2) void mfma_gemm_kernel(
    const ushort* __restrict__ A, const ushort* __restrict__ B,
    const float* __restrict__ bias, float* __restrict__ C,
    int N, int Mlimit)
{
    __shared__ __align__(16) ushort lA[128 * 64];
    __shared__ __align__(16) ushort lB[128 * 64];
    const int tid = threadIdx.x;
    const int lane = tid & 63, wid = tid >> 6;
    const int m0 = blockIdx.x << 7, n0 = blockIdx.y << 7;
    const int wm = (wid & 1) << 6, wn = (wid >> 1) << 6;

    // staging: per wave 4 insts x (A,B); inst i covers rows wid*32+i*8..+8
    const int srow = (wid << 5) + (lane >> 3);   // + i*8
    const int sj   = lane & 7;                   // LDS linear 16B-chunk slot

    f4v acc[4][4];
#pragma unroll
    for (int i = 0; i < 4; ++i)
#pragma unroll
        for (int j = 0; j < 4; ++j) acc[i][j] = (f4v){0.f, 0.f, 0.f, 0.f};

    const int fra = wm + (lane & 15);   // A frag row (+ fi*16)
    const int frb = wn + (lane & 15);   // B frag row (+ fj*16)
    const int kc  = lane >> 4;          // k-chunk within 32-k slice

    for (int k0 = 0; k0 < NK; k0 += 64) {
#pragma unroll
        for (int i = 0; i < 4; ++i) {
            const int row = srow + (i << 3);
            const int gj  = sj ^ (row & 7);     // pre-swizzled global source chunk
            const int lbase = (wid << 11) + (i << 9);   // shorts
            gload16(A + (size_t)(m0 + row) * NK + k0 + (gj << 3), &lA[lbase]);
            gload16(B + (size_t)(n0 + row) * NK + k0 + (gj << 3), &lB[lbase]);
        }
        __syncthreads();   // compiler drains vmcnt before barrier
#pragma unroll
        for (int ks = 0; ks < 2; ++ks) {
            s8v af[4], bf[4];
            const int jc = (ks << 2) + kc;
#pragma unroll
            for (int f = 0; f < 4; ++f) {
                const int ra = fra + (f << 4);
                const int rb = frb + (f << 4);
                af[f] = *(const s8v*)&lA[ra * 64 + ((jc ^ (ra & 7)) << 3)];
                bf[f] = *(const s8v*)&lB[rb * 64 + ((jc ^ (rb & 7)) << 3)];
            }
#pragma unroll
            for (int i = 0; i < 4; ++i)
#pragma unroll
                for (int j = 0; j < 4; ++j)
                    acc[i][j] = __builtin_amdgcn_mfma_f32_16x16x32_bf16(
                        af[i], bf[j], acc[i][j], 0, 0, 0);
        }
        __syncthreads();
    }

    // epilogue: C/D layout col=lane&15, row=(lane>>4)*4+reg  [m89-verified]
    const int ccol = lane & 15, crow = (lane >> 4) << 2;
#pragma unroll
    for (int j = 0; j < 4; ++j) {
        const int col = n0 + wn + (j << 4) + ccol;
        const float bv = bias[col];
#pragma unroll
        for (int i = 0; i < 4; ++i) {
#pragma unroll
            for (int r = 0; r < 4; ++r) {
                const int row = m0 + wm + (i << 4) + crow + r;
                if (row < Mlimit) C[(size_t)row * N + col] = acc[i][j][r] + bv;
            }
        }
    }
}

// ---------------------------------------------------------------------------
// Cooperative LSTM: all 20 steps in one launch. 256 blocks x 256 threads.
// Block bid: kz=bid&3 (k-split), nt=(bid>>2)&15 (32 n-cols x 4 gates),
// bt=bid>>6 (32 b-rows). Phase A: partial gemm into pbuf; grid.sync;
// Phase B (kz==0 blocks): gates = Xgate + sum(pbuf), LSTM pointwise; grid.sync.
// ---------------------------------------------------------------------------
__global__ __launch_bounds__(256) void lstm_kernel(
    const float* __restrict__ h0, const float* __restrict__ c0,
    const float* __restrict__ w_hh, const float* __restrict__ Xgate,
    float* __restrict__ Hs, float* __restrict__ cbuf,
    float* __restrict__ pbuf)
{
    cg::grid_group grid = cg::this_grid();
    __shared__ float Ht[32][34];
    __shared__ float Wt[32][32][4];
    const int tid = threadIdx.x;
    const int bid = blockIdx.x;
    const int kz = bid & 3, nt = (bid >> 2) & 15, bt = bid >> 6;
    const int b0 = bt << 5, n0 = nt << 5;
    const int tx = tid & 15, ty = tid >> 4;
    const int hlr = tid >> 3, hlc = (tid & 7) << 2;
    const int wnl = tid >> 3, wc = (tid & 7) << 2;
    const int kbeg = kz << 7;

    for (int t = 0; t < NT; ++t) {
        const float* hsrc = t ? (Hs + (size_t)(t - 1) * NB * NH) : h0;

        float acc[2][2][4];
#pragma unroll
        for (int bi = 0; bi < 2; ++bi)
#pragma unroll
            for (int ni = 0; ni < 2; ++ni)
#pragma unroll
                for (int g = 0; g < 4; ++g) acc[bi][ni][g] = 0.0f;

        for (int k0 = kbeg; k0 < kbeg + 128; k0 += 32) {
            F4 hv; hv.v = *(const float4*)(hsrc + (size_t)(b0 + hlr) * NH + k0 + hlc);
            F4 wv[4];
#pragma unroll
            for (int g = 0; g < 4; ++g)
                wv[g].v = *(const float4*)(w_hh + (size_t)(g * NH + n0 + wnl) * NK + k0 + wc);
            __syncthreads();
#pragma unroll
            for (int i = 0; i < 4; ++i) {
                Ht[hlc + i][hlr] = hv.f[i];
#pragma unroll
                for (int g = 0; g < 4; ++g) Wt[wc + i][wnl][g] = wv[g].f[i];
            }
            __syncthreads();
#pragma unroll
            for (int kk = 0; kk < 32; ++kk) {
                float2 h2 = *(const float2*)&Ht[kk][ty << 1];
                F4 w0, w1;
                w0.v = *(const float4*)&Wt[kk][tx][0];
                w1.v = *(const float4*)&Wt[kk][tx + 16][0];
#pragma unroll
                for (int g = 0; g < 4; ++g) {
                    acc[0][0][g] = fmaf(h2.x, w0.f[g], acc[0][0][g]);
                    acc[0][1][g] = fmaf(h2.x, w1.f[g], acc[0][1][g]);
                    acc[1][0][g] = fmaf(h2.y, w0.f[g], acc[1][0][g]);
                    acc[1][1][g] = fmaf(h2.y, w1.f[g], acc[1][1][g]);
                }
            }
            __syncthreads();
        }
#pragma unroll
        for (int bi = 0; bi < 2; ++bi) {
            const int b = b0 + (ty << 1) + bi;
#pragma unroll
            for (int g = 0; g < 4; ++g) {
                float* p = pbuf + (size_t)(kz * NB + b) * NG + g * NH + n0 + tx;
                p[0]  = acc[bi][0][g];
                p[16] = acc[bi][1][g];
            }
        }
        __threadfence();
        grid.sync();

        if (kz == 0) {
            const float* csrc = t ? (cbuf + (size_t)((t - 1) & 1) * NB * NH) : c0;
            float* cdst = cbuf + (size_t)(t & 1) * NB * NH;
            float* hdst = Hs + (size_t)t * NB * NH;
            const float* Xg = Xgate + (size_t)t * NB * NG;
            const int b = b0 + (tid >> 3);
            const int n = n0 + ((tid & 7) << 2);
            F4 gv[4];
#pragma unroll
            for (int g = 0; g < 4; ++g) {
                const size_t off = (size_t)b * NG + g * NH + n;
                F4 x; x.v = *(const float4*)(Xg + off);
#pragma unroll
                for (int ks = 0; ks < 4; ++ks) {
                    F4 p; p.v = *(const float4*)(pbuf + (size_t)ks * NB * NG + off);
#pragma unroll
                    for (int e = 0; e < 4; ++e) x.f[e] += p.f[e];
                }
                gv[g] = x;
            }
            F4 c; c.v = *(const float4*)(csrc + (size_t)b * NH + n);
            F4 cn, hn;
#pragma unroll
            for (int e = 0; e < 4; ++e) {
                const float ig = sigmoidf_(gv[0].f[e]);
                const float fg = sigmoidf_(gv[1].f[e]);
                const float gg = tanhf(gv[2].f[e]);
                const float og = sigmoidf_(gv[3].f[e]);
                const float cv = fg * c.f[e] + ig * gg;
                cn.f[e] = cv;
                hn.f[e] = og * tanhf(cv);
            }
            *(float4*)(cdst + (size_t)b * NH + n) = cn.v;
            *(float4*)(hdst + (size_t)b * NH + n) = hn.v;
        }
        __threadfence();
        grid.sync();
    }
}

// ---------------------------------------------------------------------------
extern "C" void kernel_launch(void* const* d_in, const int* in_sizes, int n_in,
                              void* d_out, int out_size, void* d_ws, size_t ws_size,
                              hipStream_t stream) {
    const float* features = (const float*)d_in[0];
    const int*   captions = (const int*)d_in[1];
    const int*   lengths  = (const int*)d_in[2];
    const float* h0       = (const float*)d_in[3];
    const float* c0       = (const float*)d_in[4];
    const float* embed_w  = (const float*)d_in[5];
    const float* w_ih     = (const float*)d_in[6];
    const float* w_hh     = (const float*)d_in[7];
    const float* b_ih     = (const float*)d_in[8];
    const float* b_hh     = (const float*)d_in[9];
    const float* lin_w    = (const float*)d_in[10];
    const float* lin_b    = (const float*)d_in[11];
    float* out = (float*)d_out;

    const int M3    = out_size / NV;        // packed rows (sum of lengths)
    const int mt3   = (M3 + 127) >> 7;
    const int mpad3 = mt3 << 7;

    char* p = (char*)d_ws;
    auto alloc = [&](size_t bytes) { char* r = p; p += (bytes + 255) & ~(size_t)255; return r; };
    float*  Xgate = (float*)alloc(sizeof(float) * (size_t)NT * NB * NG);   // 21 MB
    float*  Hs    = (float*)alloc(sizeof(float) * (size_t)NT * NB * NH);   // 5.2 MB
    float*  cbuf  = (float*)alloc(sizeof(float) * (size_t)2 * NB * NH);
    float*  pbuf  = (float*)alloc(sizeof(float) * (size_t)4 * NB * NG);    // 4.2 MB
    float*  bias2 = (float*)alloc(sizeof(float) * NG);
    int*    idx3  = (int*)alloc(sizeof(int) * (size_t)NT * NB);
    ushort* Xpack = (ushort*)alloc(sizeof(ushort) * (size_t)NT * NB * NK); // 2.6 MB
    ushort* Apack = (ushort*)alloc(sizeof(ushort) * (size_t)NT * NB * NK); // 2.6 MB
    ushort* Wihb  = (ushort*)alloc(sizeof(ushort) * (size_t)NG * NK);      // 2.1 MB
    ushort* Wlinb = (ushort*)alloc(sizeof(ushort) * (size_t)NV * NK);      // 32.8 MB

    prep_kernel<<<1, 256, 0, stream>>>(lengths, b_ih, b_hh, bias2, idx3, mpad3);
    wconv_kernel<<<(NG * NK / 8 + 255) / 256, 256, 0, stream>>>(w_ih, Wihb, NG * NK / 8);
    wconv_kernel<<<(NV * NK / 8 + 255) / 256, 256, 0, stream>>>(lin_w, Wlinb, NV * NK / 8);
    xpack_kernel<<<NT * NB * 64 / 256, 256, 0, stream>>>(features, captions, embed_w, Xpack);

    // Xgate = Xpack @ Wihb^T + bias2   [2560 x 2048]
    mfma_gemm_kernel<<<dim3(NT * NB / 128, NG / 128), 256, 0, stream>>>(
        Xpack, Wihb, bias2, Xgate, NG, NT * NB);

    // full recurrence, one cooperative launch
    {
        void* args[] = {(void*)&h0, (void*)&c0, (void*)&w_hh, (void*)&Xgate,
                        (void*)&Hs, (void*)&cbuf, (void*)&pbuf};
        hipLaunchCooperativeKernel((const void*)lstm_kernel, dim3(256), dim3(256),
                                   args, 0, stream);
    }

    gather_kernel<<<mpad3 * 64 / 256, 256, 0, stream>>>(Hs, idx3, Apack);

    // out = Apack @ Wlinb^T + lin_b   [M3 x 32000]
    mfma_gemm_kernel<<<dim3(mt3, NV / 128), 256, 0, stream>>>(
        Apack, Wlinb, lin_b, out, NV, M3);
}

// Round 6
// 831.608 us; speedup vs baseline: 3.3675x; 3.3675x over previous
//
#include <hip/hip_runtime.h>
#include <math.h>

// Problem constants: B=128, MAXLEN=20, E=H=512, V=32000
#define NB 128
#define NT 20
#define NH 512
#define NV 32000
#define NG 2048   // 4*H
#define NK 512    // E == H

typedef __attribute__((ext_vector_type(8))) short s8v;   // 8 x bf16 (4 VGPR)
typedef __attribute__((ext_vector_type(4))) float f4v;   // MFMA accumulator
union F4 { float4 v; float f[4]; };

__device__ __forceinline__ float sigmoidf_(float x) { return 1.0f / (1.0f + expf(-x)); }

__device__ __forceinline__ ushort f2bf(float f) {   // round-to-nearest-even
    union { float f; unsigned u; } x; x.f = f;
    unsigned r = x.u + 0x7fffu + ((x.u >> 16) & 1u);
    return (ushort)(r >> 16);
}
__device__ __forceinline__ float bf2f(ushort b) {
    union { unsigned u; float f; } x; x.u = ((unsigned)b) << 16; return x.f;
}

__device__ __forceinline__ void gload16(const void* g, void* l) {
    // async global->LDS, 16B/lane, dest = wave-uniform base + lane*16
    __builtin_amdgcn_global_load_lds((const __attribute__((address_space(1))) void*)g,
                                     (__attribute__((address_space(3))) void*)l, 16, 0, 0);
}

// gate-interleave permutation: row r = g*512+n  ->  (n>>5)*128 + g*32 + (n&31)
__device__ __forceinline__ int permrow(int r) {
    return (((r & 511) >> 5) << 7) + ((r >> 9) << 5) + (r & 31);
}

// ---------------------------------------------------------------------------
// prep: bias_r[perm(j)] = b_ih[j]+b_hh[j]; idx3[r] = t*NB+b for packed row r
// (pack_padded order), padded with -1 up to mpad3.
// ---------------------------------------------------------------------------
__global__ __launch_bounds__(256) void prep_kernel(
    const int* __restrict__ lengths, const float* __restrict__ b_ih,
    const float* __restrict__ b_hh, float* __restrict__ bias_r,
    int* __restrict__ idx3, int mpad3)
{
    const int tid = threadIdx.x;
    for (int j = tid; j < NG; j += 256) bias_r[permrow(j)] = b_ih[j] + b_hh[j];

    __shared__ unsigned long long s_mask[4];
    __shared__ int s_off;
    if (tid == 0) s_off = 0;
    const int len  = (tid < NB) ? lengths[tid] : 0;
    const int lane = tid & 63, wv = tid >> 6;
    __syncthreads();
    for (int t = 0; t < NT; ++t) {
        const bool flag = (len > t);
        unsigned long long bm = __ballot(flag ? 1 : 0);
        if (lane == 0) s_mask[wv] = bm;
        __syncthreads();
        int pos = s_off;
        for (int w = 0; w < wv; ++w) pos += __popcll(s_mask[w]);
        pos += __popcll(bm & ((1ull << lane) - 1ull));
        if (flag) idx3[pos] = t * NB + tid;
        __syncthreads();
        if (tid == 0) {
            int tot = 0;
            for (int w = 0; w < 4; ++w) tot += __popcll(s_mask[w]);
            s_off += tot;
        }
        __syncthreads();
    }
    for (int m = s_off + tid; m < mpad3; m += 256) idx3[m] = -1;
}

// ---------------------------------------------------------------------------
// xpack: Xpack[t*128+b][:] = bf16( t==0 ? features[b] : embed_w[cap[b][t-1]] )
// ---------------------------------------------------------------------------
__global__ __launch_bounds__(256) void xpack_kernel(
    const float* __restrict__ features, const int* __restrict__ captions,
    const float* __restrict__ embed_w, ushort* __restrict__ Xpack)
{
    const int gid = blockIdx.x * 256 + threadIdx.x;  // 0..163839
    const int r = gid >> 6, cc = (gid & 63) << 3;
    const int t = r >> 7, b = r & 127;
    const float* src = (t == 0) ? (features + (size_t)b * NK)
                                : (embed_w + (size_t)captions[b * NT + t - 1] * NK);
    F4 v0, v1; v0.v = *(const float4*)(src + cc); v1.v = *(const float4*)(src + cc + 4);
    s8v o;
#pragma unroll
    for (int e = 0; e < 4; ++e) { o[e] = (short)f2bf(v0.f[e]); o[e + 4] = (short)f2bf(v1.f[e]); }
    *(s8v*)(Xpack + (size_t)r * NK + cc) = o;
}

// ---------------------------------------------------------------------------
// wconv: fp32 -> bf16 (plain).  wconv_r: fp32 -> bf16 with gate-perm rows.
// ---------------------------------------------------------------------------
__global__ __launch_bounds__(256) void wconv_kernel(
    const float* __restrict__ in, ushort* __restrict__ outw, int n8)
{
    const int gid = blockIdx.x * 256 + threadIdx.x;
    if (gid >= n8) return;
    const int i = gid << 3;
    F4 v0, v1; v0.v = *(const float4*)(in + i); v1.v = *(const float4*)(in + i + 4);
    s8v o;
#pragma unroll
    for (int e = 0; e < 4; ++e) { o[e] = (short)f2bf(v0.f[e]); o[e + 4] = (short)f2bf(v1.f[e]); }
    *(s8v*)(outw + i) = o;
}

__global__ __launch_bounds__(256) void wconv_r_kernel(
    const float* __restrict__ in, ushort* __restrict__ outw)
{
    const int gid = blockIdx.x * 256 + threadIdx.x;   // NG*64 threads
    const int row = gid >> 6, cc = (gid & 63) << 3;
    const int orow = permrow(row);
    F4 v0, v1;
    v0.v = *(const float4*)(in + (size_t)row * NK + cc);
    v1.v = *(const float4*)(in + (size_t)row * NK + cc + 4);
    s8v o;
#pragma unroll
    for (int e = 0; e < 4; ++e) { o[e] = (short)f2bf(v0.f[e]); o[e + 4] = (short)f2bf(v1.f[e]); }
    *(s8v*)(outw + (size_t)orow * NK + cc) = o;
}

// ---------------------------------------------------------------------------
// split: HbfAll[0]/Hlo[0] = split(h0); cbuf slot0 = c0
// ---------------------------------------------------------------------------
__global__ __launch_bounds__(256) void split_kernel(
    const float* __restrict__ h0, const float* __restrict__ c0,
    ushort* __restrict__ Hhi, ushort* __restrict__ Hlo, float* __restrict__ cb0)
{
    const int gid = blockIdx.x * 256 + threadIdx.x;  // 8192 threads
    const int i = gid << 3;
    F4 v0, v1; v0.v = *(const float4*)(h0 + i); v1.v = *(const float4*)(h0 + i + 4);
    s8v hi, lo;
#pragma unroll
    for (int e = 0; e < 8; ++e) {
        float f = (e < 4) ? v0.f[e] : v1.f[e - 4];
        ushort h = f2bf(f);
        hi[e] = (short)h;
        lo[e] = (short)f2bf(f - bf2f(h));
    }
    *(s8v*)(Hhi + i) = hi;
    *(s8v*)(Hlo + i) = lo;
    F4 c0a, c0b; c0a.v = *(const float4*)(c0 + i); c0b.v = *(const float4*)(c0 + i + 4);
    *(float4*)(cb0 + i) = c0a.v;
    *(float4*)(cb0 + i + 4) = c0b.v;
}

// ---------------------------------------------------------------------------
// gather: Apack[r][:] = HbfAll[idx3[r]+NB][:] (bf16 copy) or zeros for pads
// ---------------------------------------------------------------------------
__global__ __launch_bounds__(256) void gather_kernel(
    const ushort* __restrict__ Hhi, const int* __restrict__ idx3,
    ushort* __restrict__ Apack)
{
    const int gid = blockIdx.x * 256 + threadIdx.x;
    const int r = gid >> 6, cc = (gid & 63) << 3;
    const int src = idx3[r];
    s8v o;
    if (src < 0) {
#pragma unroll
        for (int e = 0; e < 8; ++e) o[e] = 0;
    } else {
        o = *(const s8v*)(Hhi + (size_t)(src + NB) * NH + cc);
    }
    *(s8v*)(Apack + (size_t)r * NK + cc) = o;
}

// ---------------------------------------------------------------------------
// bf16 MFMA GEMM: C[m][n] = sum_k A[m][k]*B[n][k] + bias[n]   (K = 512)
// 128x128 tile, BK=64, 4 waves (2x2 of 64x64), 16x16x32 MFMA, m97 structure.
// ---------------------------------------------------------------------------
__global__ __launch_bounds__(256, 2) void mfma_gemm_kernel(
    const ushort* __restrict__ A, const ushort* __restrict__ B,
    const float* __restrict__ bias, float* __restrict__ C,
    int N, int Mlimit)
{
    __shared__ __align__(16) ushort lA[128 * 64];
    __shared__ __align__(16) ushort lB[128 * 64];
    const int tid = threadIdx.x;
    const int lane = tid & 63, wid = tid >> 6;
    const int m0 = blockIdx.x << 7, n0 = blockIdx.y << 7;
    const int wm = (wid & 1) << 6, wn = (wid >> 1) << 6;

    const int srow = (wid << 5) + (lane >> 3);   // + i*8
    const int sj   = lane & 7;

    f4v acc[4][4];
#pragma unroll
    for (int i = 0; i < 4; ++i)
#pragma unroll
        for (int j = 0; j < 4; ++j) acc[i][j] = (f4v){0.f, 0.f, 0.f, 0.f};

    const int fra = wm + (lane & 15);
    const int frb = wn + (lane & 15);
    const int kc  = lane >> 4;

    for (int k0 = 0; k0 < NK; k0 += 64) {
#pragma unroll
        for (int i = 0; i < 4; ++i) {
            const int row = srow + (i << 3);
            const int gj  = sj ^ (row & 7);
            const int lbase = (wid << 11) + (i << 9);
            gload16(A + (size_t)(m0 + row) * NK + k0 + (gj << 3), &lA[lbase]);
            gload16(B + (size_t)(n0 + row) * NK + k0 + (gj << 3), &lB[lbase]);
        }
        __syncthreads();
#pragma unroll
        for (int ks = 0; ks < 2; ++ks) {
            s8v af[4], bf[4];
            const int jc = (ks << 2) + kc;
#pragma unroll
            for (int f = 0; f < 4; ++f) {
                const int ra = fra + (f << 4);
                const int rb = frb + (f << 4);
                af[f] = *(const s8v*)&lA[ra * 64 + ((jc ^ (ra & 7)) << 3)];
                bf[f] = *(const s8v*)&lB[rb * 64 + ((jc ^ (rb & 7)) << 3)];
            }
#pragma unroll
            for (int i = 0; i < 4; ++i)
#pragma unroll
                for (int j = 0; j < 4; ++j)
                    acc[i][j] = __builtin_amdgcn_mfma_f32_16x16x32_bf16(
                        af[i], bf[j], acc[i][j], 0, 0, 0);
        }
        __syncthreads();
    }

    const int ccol = lane & 15, crow = (lane >> 4) << 2;
#pragma unroll
    for (int j = 0; j < 4; ++j) {
        const int col = n0 + wn + (j << 4) + ccol;
        const float bv = bias[col];
#pragma unroll
        for (int i = 0; i < 4; ++i) {
#pragma unroll
            for (int r = 0; r < 4; ++r) {
                const int row = m0 + wm + (i << 4) + crow + r;
                if (row < Mlimit) C[(size_t)row * N + col] = acc[i][j][r] + bv;
            }
        }
    }
}

// ---------------------------------------------------------------------------
// rec_step: one LSTM step.  16 blocks (j = 32-hcol slice), 4 waves x 32 rows.
// gates = [Ahi + Alo] @ Whr[j*128..+128]^T + Xg;  cell fused in epilogue.
// Whr rows gate-interleaved: block cols 0..31=i, 32..63=f, 64..95=g, 96..127=o
// for h-cols j*32..j*32+31.
// ---------------------------------------------------------------------------
__global__ __launch_bounds__(256, 2) void rec_step_kernel(
    const ushort* __restrict__ Ahi, const ushort* __restrict__ Alo,
    const ushort* __restrict__ Whr, const float* __restrict__ Xg,
    const float* __restrict__ cprev, float* __restrict__ cnext,
    ushort* __restrict__ Hhi_out, ushort* __restrict__ Hlo_out)
{
    __shared__ __align__(16) ushort lAh[128 * 64];
    __shared__ __align__(16) ushort lAl[128 * 64];
    __shared__ __align__(16) ushort lB[128 * 64];
    const int tid = threadIdx.x;
    const int lane = tid & 63, wid = tid >> 6;
    const int n0 = blockIdx.x << 7;              // block col base (128 cols)
    const int wm = wid << 5;                     // wave rows 32

    const int srow = (wid << 5) + (lane >> 3);   // + i*8
    const int sj   = lane & 7;

    f4v acc[2][8];
#pragma unroll
    for (int i = 0; i < 2; ++i)
#pragma unroll
        for (int j = 0; j < 8; ++j) acc[i][j] = (f4v){0.f, 0.f, 0.f, 0.f};

    const int fra = wm + (lane & 15);   // A frag row (+ fi*16)
    const int frb = lane & 15;          // B frag row (+ fj*16), block-local
    const int kc  = lane >> 4;

    for (int k0 = 0; k0 < NK; k0 += 64) {
#pragma unroll
        for (int i = 0; i < 4; ++i) {
            const int row = srow + (i << 3);
            const int gj  = sj ^ (row & 7);
            const int lbase = (wid << 11) + (i << 9);
            gload16(Ahi + (size_t)row * NK + k0 + (gj << 3), &lAh[lbase]);
            gload16(Alo + (size_t)row * NK + k0 + (gj << 3), &lAl[lbase]);
            gload16(Whr + (size_t)(n0 + row) * NK + k0 + (gj << 3), &lB[lbase]);
        }
        __syncthreads();
#pragma unroll
        for (int ks = 0; ks < 2; ++ks) {
            const int jc = (ks << 2) + kc;
            s8v ah[2], al[2];
#pragma unroll
            for (int fi = 0; fi < 2; ++fi) {
                const int ra = fra + (fi << 4);
                const int off = ra * 64 + ((jc ^ (ra & 7)) << 3);
                ah[fi] = *(const s8v*)&lAh[off];
                al[fi] = *(const s8v*)&lAl[off];
            }
#pragma unroll
            for (int fj = 0; fj < 8; ++fj) {
                const int rb = frb + (fj << 4);
                s8v bf = *(const s8v*)&lB[rb * 64 + ((jc ^ (rb & 7)) << 3)];
#pragma unroll
                for (int fi = 0; fi < 2; ++fi) {
                    acc[fi][fj] = __builtin_amdgcn_mfma_f32_16x16x32_bf16(
                        ah[fi], bf, acc[fi][fj], 0, 0, 0);
                    acc[fi][fj] = __builtin_amdgcn_mfma_f32_16x16x32_bf16(
                        al[fi], bf, acc[fi][fj], 0, 0, 0);
                }
            }
        }
        __syncthreads();
    }

    // epilogue: cell.  C-layout col=lane&15, row=(lane>>4)*4+r.
    const int ccol = lane & 15, crow = (lane >> 4) << 2;
#pragma unroll
    for (int fi = 0; fi < 2; ++fi) {
#pragma unroll
        for (int fj = 0; fj < 2; ++fj) {
            const int hcol = (int)(blockIdx.x << 5) + (fj << 4) + ccol; // global h col
            const int colI = n0 + (fj << 4) + ccol;                     // Xg col, gate i
#pragma unroll
            for (int r = 0; r < 4; ++r) {
                const int b = wm + (fi << 4) + crow + r;
                const float* xg = Xg + (size_t)b * NG + colI;
                const float iv = acc[fi][fj][r]     + xg[0];
                const float fv = acc[fi][fj + 2][r] + xg[32];
                const float gv = acc[fi][fj + 4][r] + xg[64];
                const float ov = acc[fi][fj + 6][r] + xg[96];
                const float cp = cprev[(size_t)b * NH + hcol];
                const float cn = sigmoidf_(fv) * cp + sigmoidf_(iv) * tanhf(gv);
                const float hn = sigmoidf_(ov) * tanhf(cn);
                cnext[(size_t)b * NH + hcol] = cn;
                const ushort hb = f2bf(hn);
                Hhi_out[(size_t)b * NH + hcol] = hb;
                Hlo_out[(size_t)b * NH + hcol] = f2bf(hn - bf2f(hb));
            }
        }
    }
}

// ---------------------------------------------------------------------------
extern "C" void kernel_launch(void* const* d_in, const int* in_sizes, int n_in,
                              void* d_out, int out_size, void* d_ws, size_t ws_size,
                              hipStream_t stream) {
    const float* features = (const float*)d_in[0];
    const int*   captions = (const int*)d_in[1];
    const int*   lengths  = (const int*)d_in[2];
    const float* h0       = (const float*)d_in[3];
    const float* c0       = (const float*)d_in[4];
    const float* embed_w  = (const float*)d_in[5];
    const float* w_ih     = (const float*)d_in[6];
    const float* w_hh     = (const float*)d_in[7];
    const float* b_ih     = (const float*)d_in[8];
    const float* b_hh     = (const float*)d_in[9];
    const float* lin_w    = (const float*)d_in[10];
    const float* lin_b    = (const float*)d_in[11];
    float* out = (float*)d_out;

    const int M3    = out_size / NV;        // packed rows (sum of lengths)
    const int mt3   = (M3 + 127) >> 7;
    const int mpad3 = mt3 << 7;

    char* p = (char*)d_ws;
    auto alloc = [&](size_t bytes) { char* r = p; p += (bytes + 255) & ~(size_t)255; return r; };
    float*  Xgate = (float*)alloc(sizeof(float) * (size_t)NT * NB * NG);        // 21 MB
    ushort* HbfA  = (ushort*)alloc(sizeof(ushort) * (size_t)(NT + 1) * NB * NH); // 2.75 MB
    ushort* HloA  = (ushort*)alloc(sizeof(ushort) * (size_t)(NT + 1) * NB * NH); // 2.75 MB
    float*  cbuf  = (float*)alloc(sizeof(float) * (size_t)2 * NB * NH);
    float*  biasr = (float*)alloc(sizeof(float) * NG);
    int*    idx3  = (int*)alloc(sizeof(int) * (size_t)NT * NB);
    ushort* Xpack = (ushort*)alloc(sizeof(ushort) * (size_t)NT * NB * NK);      // 2.6 MB
    ushort* Apack = (ushort*)alloc(sizeof(ushort) * (size_t)mpad3 * NK);        // 1.7 MB
    ushort* Wihr  = (ushort*)alloc(sizeof(ushort) * (size_t)NG * NK);           // 2.1 MB
    ushort* Whr   = (ushort*)alloc(sizeof(ushort) * (size_t)NG * NK);           // 2.1 MB
    ushort* Wlinb = (ushort*)alloc(sizeof(ushort) * (size_t)NV * NK);           // 32.8 MB

    prep_kernel<<<1, 256, 0, stream>>>(lengths, b_ih, b_hh, biasr, idx3, mpad3);
    wconv_r_kernel<<<NG * 64 / 256, 256, 0, stream>>>(w_ih, Wihr);
    wconv_r_kernel<<<NG * 64 / 256, 256, 0, stream>>>(w_hh, Whr);
    wconv_kernel<<<(NV * NK / 8 + 255) / 256, 256, 0, stream>>>(lin_w, Wlinb, NV * NK / 8);
    xpack_kernel<<<NT * NB * 64 / 256, 256, 0, stream>>>(features, captions, embed_w, Xpack);
    split_kernel<<<NB * NH / 8 / 256, 256, 0, stream>>>(h0, c0, HbfA, HloA, cbuf);

    // Xgate[t*B+b][perm-col] = Xpack @ Wihr^T + biasr   [2560 x 2048]
    mfma_gemm_kernel<<<dim3(NT * NB / 128, NG / 128), 256, 0, stream>>>(
        Xpack, Wihr, biasr, Xgate, NG, NT * NB);

    // recurrence: 20 fused gemm+cell launches (coherence via kernel boundaries)
    for (int t = 0; t < NT; ++t) {
        const ushort* Ahi = HbfA + (size_t)t * NB * NH;
        const ushort* Alo = HloA + (size_t)t * NB * NH;
        const float*  cpv = cbuf + (size_t)(t & 1) * NB * NH;
        float*        cnx = cbuf + (size_t)((t + 1) & 1) * NB * NH;
        rec_step_kernel<<<16, 256, 0, stream>>>(
            Ahi, Alo, Whr, Xgate + (size_t)t * NB * NG, cpv, cnx,
            HbfA + (size_t)(t + 1) * NB * NH, HloA + (size_t)(t + 1) * NB * NH);
    }

    gather_kernel<<<mpad3 * 64 / 256, 256, 0, stream>>>(HbfA, idx3, Apack);

    // out = Apack @ Wlinb^T + lin_b   [M3 x 32000]
    mfma_gemm_kernel<<<dim3(mt3, NV / 128), 256, 0, stream>>>(
        Apack, Wlinb, lin_b, out, NV, M3);
}

// Round 7
// 691.257 us; speedup vs baseline: 4.0513x; 1.2030x over previous
//
#include <hip/hip_runtime.h>
#include <math.h>

// Problem constants: B=128, MAXLEN=20, E=H=512, V=32000
#define NB 128
#define NT 20
#define NH 512
#define NV 32000
#define NG 2048   // 4*H
#define NK 512    // E == H

typedef __attribute__((ext_vector_type(8))) short s8v;   // 8 x bf16 (4 VGPR)
typedef __attribute__((ext_vector_type(4))) float f4v;   // MFMA accumulator
union F4 { float4 v; float f[4]; };

__device__ __forceinline__ float sigmoidf_(float x) { return 1.0f / (1.0f + expf(-x)); }

__device__ __forceinline__ ushort f2bf(float f) {   // round-to-nearest-even
    union { float f; unsigned u; } x; x.f = f;
    unsigned r = x.u + 0x7fffu + ((x.u >> 16) & 1u);
    return (ushort)(r >> 16);
}
__device__ __forceinline__ float bf2f(ushort b) {
    union { unsigned u; float f; } x; x.u = ((unsigned)b) << 16; return x.f;
}

__device__ __forceinline__ void gload16(const void* g, void* l) {
    // async global->LDS, 16B/lane, dest = wave-uniform base + lane*16
    __builtin_amdgcn_global_load_lds((const __attribute__((address_space(1))) void*)g,
                                     (__attribute__((address_space(3))) void*)l, 16, 0, 0);
}

// gate-interleave permutation: row r = g*512+n  ->  (n>>5)*128 + g*32 + (n&31)
__device__ __forceinline__ int permrow(int r) {
    return (((r & 511) >> 5) << 7) + ((r >> 9) << 5) + (r & 31);
}

// ---------------------------------------------------------------------------
// prep: bias_r[perm(j)] = b_ih[j]+b_hh[j]; idx3[r] = t*NB+b for packed row r
// ---------------------------------------------------------------------------
__global__ __launch_bounds__(256) void prep_kernel(
    const int* __restrict__ lengths, const float* __restrict__ b_ih,
    const float* __restrict__ b_hh, float* __restrict__ bias_r,
    int* __restrict__ idx3, int mpad3)
{
    const int tid = threadIdx.x;
    for (int j = tid; j < NG; j += 256) bias_r[permrow(j)] = b_ih[j] + b_hh[j];

    __shared__ unsigned long long s_mask[4];
    __shared__ int s_off;
    if (tid == 0) s_off = 0;
    const int len  = (tid < NB) ? lengths[tid] : 0;
    const int lane = tid & 63, wv = tid >> 6;
    __syncthreads();
    for (int t = 0; t < NT; ++t) {
        const bool flag = (len > t);
        unsigned long long bm = __ballot(flag ? 1 : 0);
        if (lane == 0) s_mask[wv] = bm;
        __syncthreads();
        int pos = s_off;
        for (int w = 0; w < wv; ++w) pos += __popcll(s_mask[w]);
        pos += __popcll(bm & ((1ull << lane) - 1ull));
        if (flag) idx3[pos] = t * NB + tid;
        __syncthreads();
        if (tid == 0) {
            int tot = 0;
            for (int w = 0; w < 4; ++w) tot += __popcll(s_mask[w]);
            s_off += tot;
        }
        __syncthreads();
    }
    for (int m = s_off + tid; m < mpad3; m += 256) idx3[m] = -1;
}

// ---------------------------------------------------------------------------
// xpack: Xpack[t*128+b][:] = bf16( t==0 ? features[b] : embed_w[cap[b][t-1]] )
// ---------------------------------------------------------------------------
__global__ __launch_bounds__(256) void xpack_kernel(
    const float* __restrict__ features, const int* __restrict__ captions,
    const float* __restrict__ embed_w, ushort* __restrict__ Xpack)
{
    const int gid = blockIdx.x * 256 + threadIdx.x;  // 0..163839
    const int r = gid >> 6, cc = (gid & 63) << 3;
    const int t = r >> 7, b = r & 127;
    const float* src = (t == 0) ? (features + (size_t)b * NK)
                                : (embed_w + (size_t)captions[b * NT + t - 1] * NK);
    F4 v0, v1; v0.v = *(const float4*)(src + cc); v1.v = *(const float4*)(src + cc + 4);
    s8v o;
#pragma unroll
    for (int e = 0; e < 4; ++e) { o[e] = (short)f2bf(v0.f[e]); o[e + 4] = (short)f2bf(v1.f[e]); }
    *(s8v*)(Xpack + (size_t)r * NK + cc) = o;
}

// ---------------------------------------------------------------------------
// wconv: fp32 -> bf16 (plain).  wconv_r: fp32 -> bf16 with gate-perm rows.
// ---------------------------------------------------------------------------
__global__ __launch_bounds__(256) void wconv_kernel(
    const float* __restrict__ in, ushort* __restrict__ outw, int n8)
{
    const int gid = blockIdx.x * 256 + threadIdx.x;
    if (gid >= n8) return;
    const int i = gid << 3;
    F4 v0, v1; v0.v = *(const float4*)(in + i); v1.v = *(const float4*)(in + i + 4);
    s8v o;
#pragma unroll
    for (int e = 0; e < 4; ++e) { o[e] = (short)f2bf(v0.f[e]); o[e + 4] = (short)f2bf(v1.f[e]); }
    *(s8v*)(outw + i) = o;
}

__global__ __launch_bounds__(256) void wconv_r_kernel(
    const float* __restrict__ in, ushort* __restrict__ outw)
{
    const int gid = blockIdx.x * 256 + threadIdx.x;   // NG*64 threads
    const int row = gid >> 6, cc = (gid & 63) << 3;
    const int orow = permrow(row);
    F4 v0, v1;
    v0.v = *(const float4*)(in + (size_t)row * NK + cc);
    v1.v = *(const float4*)(in + (size_t)row * NK + cc + 4);
    s8v o;
#pragma unroll
    for (int e = 0; e < 4; ++e) { o[e] = (short)f2bf(v0.f[e]); o[e + 4] = (short)f2bf(v1.f[e]); }
    *(s8v*)(outw + (size_t)orow * NK + cc) = o;
}

// ---------------------------------------------------------------------------
// split: HbfAll[0]/Hlo[0] = split(h0); cbuf slot0 = c0
// ---------------------------------------------------------------------------
__global__ __launch_bounds__(256) void split_kernel(
    const float* __restrict__ h0, const float* __restrict__ c0,
    ushort* __restrict__ Hhi, ushort* __restrict__ Hlo, float* __restrict__ cb0)
{
    const int gid = blockIdx.x * 256 + threadIdx.x;  // 8192 threads
    const int i = gid << 3;
    F4 v0, v1; v0.v = *(const float4*)(h0 + i); v1.v = *(const float4*)(h0 + i + 4);
    s8v hi, lo;
#pragma unroll
    for (int e = 0; e < 8; ++e) {
        float f = (e < 4) ? v0.f[e] : v1.f[e - 4];
        ushort h = f2bf(f);
        hi[e] = (short)h;
        lo[e] = (short)f2bf(f - bf2f(h));
    }
    *(s8v*)(Hhi + i) = hi;
    *(s8v*)(Hlo + i) = lo;
    F4 c0a, c0b; c0a.v = *(const float4*)(c0 + i); c0b.v = *(const float4*)(c0 + i + 4);
    *(float4*)(cb0 + i) = c0a.v;
    *(float4*)(cb0 + i + 4) = c0b.v;
}

// ---------------------------------------------------------------------------
// gather: Apack[r][:] = HbfAll[idx3[r]+NB][:] (bf16 copy) or zeros for pads
// ---------------------------------------------------------------------------
__global__ __launch_bounds__(256) void gather_kernel(
    const ushort* __restrict__ Hhi, const int* __restrict__ idx3,
    ushort* __restrict__ Apack)
{
    const int gid = blockIdx.x * 256 + threadIdx.x;
    const int r = gid >> 6, cc = (gid & 63) << 3;
    const int src = idx3[r];
    s8v o;
    if (src < 0) {
#pragma unroll
        for (int e = 0; e < 8; ++e) o[e] = 0;
    } else {
        o = *(const s8v*)(Hhi + (size_t)(src + NB) * NH + cc);
    }
    *(s8v*)(Apack + (size_t)r * NK + cc) = o;
}

// ---------------------------------------------------------------------------
// bf16 MFMA GEMM: C[m][n] = sum_k A[m][k]*B[n][k] + bias[n]   (K = 512)
// 128x128 tile, BK=64, 4 waves (2x2 of 64x64), 16x16x32 MFMA, m97 structure.
// ---------------------------------------------------------------------------
__global__ __launch_bounds__(256, 2) void mfma_gemm_kernel(
    const ushort* __restrict__ A, const ushort* __restrict__ B,
    const float* __restrict__ bias, float* __restrict__ C,
    int N, int Mlimit)
{
    __shared__ __align__(16) ushort lA[128 * 64];
    __shared__ __align__(16) ushort lB[128 * 64];
    const int tid = threadIdx.x;
    const int lane = tid & 63, wid = tid >> 6;
    const int m0 = blockIdx.x << 7, n0 = blockIdx.y << 7;
    const int wm = (wid & 1) << 6, wn = (wid >> 1) << 6;

    const int srow = (wid << 5) + (lane >> 3);   // + i*8
    const int sj   = lane & 7;

    f4v acc[4][4];
#pragma unroll
    for (int i = 0; i < 4; ++i)
#pragma unroll
        for (int j = 0; j < 4; ++j) acc[i][j] = (f4v){0.f, 0.f, 0.f, 0.f};

    const int fra = wm + (lane & 15);
    const int frb = wn + (lane & 15);
    const int kc  = lane >> 4;

    for (int k0 = 0; k0 < NK; k0 += 64) {
#pragma unroll
        for (int i = 0; i < 4; ++i) {
            const int row = srow + (i << 3);
            const int gj  = sj ^ (row & 7);
            const int lbase = (wid << 11) + (i << 9);
            gload16(A + (size_t)(m0 + row) * NK + k0 + (gj << 3), &lA[lbase]);
            gload16(B + (size_t)(n0 + row) * NK + k0 + (gj << 3), &lB[lbase]);
        }
        __syncthreads();
#pragma unroll
        for (int ks = 0; ks < 2; ++ks) {
            s8v af[4], bf[4];
            const int jc = (ks << 2) + kc;
#pragma unroll
            for (int f = 0; f < 4; ++f) {
                const int ra = fra + (f << 4);
                const int rb = frb + (f << 4);
                af[f] = *(const s8v*)&lA[ra * 64 + ((jc ^ (ra & 7)) << 3)];
                bf[f] = *(const s8v*)&lB[rb * 64 + ((jc ^ (rb & 7)) << 3)];
            }
#pragma unroll
            for (int i = 0; i < 4; ++i)
#pragma unroll
                for (int j = 0; j < 4; ++j)
                    acc[i][j] = __builtin_amdgcn_mfma_f32_16x16x32_bf16(
                        af[i], bf[j], acc[i][j], 0, 0, 0);
        }
        __syncthreads();
    }

    const int ccol = lane & 15, crow = (lane >> 4) << 2;
#pragma unroll
    for (int j = 0; j < 4; ++j) {
        const int col = n0 + wn + (j << 4) + ccol;
        const float bv = bias[col];
#pragma unroll
        for (int i = 0; i < 4; ++i) {
#pragma unroll
            for (int r = 0; r < 4; ++r) {
                const int row = m0 + wm + (i << 4) + crow + r;
                if (row < Mlimit) C[(size_t)row * N + col] = acc[i][j][r] + bv;
            }
        }
    }
}

// ---------------------------------------------------------------------------
// rec_step2: one LSTM step, latency-optimized.
// Grid 32: bh=blockIdx.x>>4 (64 b-rows), nt=blockIdx.x&15 (128 gate-cols =
// 32 hcols x 4 gates, gate-interleaved Whr).  4 waves x 16 rows each.
// Double-buffered LDS staging with counted vmcnt (never 0 mid-loop) + raw
// s_barrier so prefetch of k-tile t+1 overlaps MFMA on tile t.
// ---------------------------------------------------------------------------
__global__ __launch_bounds__(256) void rec_step2_kernel(
    const ushort* __restrict__ Ahi, const ushort* __restrict__ Alo,
    const ushort* __restrict__ Whr, const float* __restrict__ Xg,
    const float* __restrict__ cprev, float* __restrict__ cnext,
    ushort* __restrict__ Hhi_out, ushort* __restrict__ Hlo_out)
{
    __shared__ __align__(16) ushort lAh[2][64 * 64];   // 16 KB
    __shared__ __align__(16) ushort lAl[2][64 * 64];   // 16 KB
    __shared__ __align__(16) ushort lW [2][128 * 64];  // 32 KB
    const int tid = threadIdx.x;
    const int lane = tid & 63, wid = tid >> 6;
    const int bh = blockIdx.x >> 4, nt = blockIdx.x & 15;
    const int rbase = bh << 6;           // global b-row base (0 or 64)
    const int n0 = nt << 7;              // Whr row base (gate-interleaved cols)

    // staging geometry: each inst covers 8 rows x 64 cols (64 lanes x 16B).
    // LDS[row][slot] = G[row][slot ^ (row&7)]; here row&7 == lane>>3.
    const int gj8 = ((lane & 7) ^ (lane >> 3)) << 3;   // swizzled source chunk (shorts)
    const int lrow = lane >> 3;                        // row within 8-row group

    // fragment geometry
    const int ra = (wid << 4) + (lane & 15);   // A local row (wave owns 16 rows)
    const int rb = lane & 15;                  // W local row base (+ fj*16)
    const int kc = lane >> 4;

    f4v acc[8];
#pragma unroll
    for (int j = 0; j < 8; ++j) acc[j] = (f4v){0.f, 0.f, 0.f, 0.f};

    // stage one 64-k tile into buffer `buf`: per wave 2xAhi + 2xAlo + 4xW insts
    auto stage = [&](int buf, int k0) {
#pragma unroll
        for (int i = 0; i < 2; ++i) {
            const int r0 = (wid << 4) + (i << 3);              // A local row base
            const size_t goff = (size_t)(rbase + r0 + lrow) * NK + k0 + gj8;
            gload16(Ahi + goff, &lAh[buf][r0 << 6]);
            gload16(Alo + goff, &lAl[buf][r0 << 6]);
        }
#pragma unroll
        for (int j = 0; j < 4; ++j) {
            const int r0 = (wid << 5) + (j << 3);              // W local row base
            gload16(Whr + (size_t)(n0 + r0 + lrow) * NK + k0 + gj8,
                    &lW[buf][r0 << 6]);
        }
    };

    stage(0, 0);
    for (int it = 0; it < 8; ++it) {
        const int cur = it & 1;
        if (it < 7) {
            stage(cur ^ 1, (it + 1) << 6);
            asm volatile("s_waitcnt vmcnt(8)" ::: "memory");   // cur-buf landed
        } else {
            asm volatile("s_waitcnt vmcnt(0)" ::: "memory");
        }
        asm volatile("s_barrier" ::: "memory");                // all waves landed
#pragma unroll
        for (int ks = 0; ks < 2; ++ks) {
            const int jc = (ks << 2) + kc;
            const int aoff = ra * 64 + ((jc ^ (ra & 7)) << 3);
            s8v ah = *(const s8v*)&lAh[cur][aoff];
            s8v al = *(const s8v*)&lAl[cur][aoff];
#pragma unroll
            for (int fj = 0; fj < 8; ++fj) {
                const int rw = rb + (fj << 4);
                s8v wf = *(const s8v*)&lW[cur][rw * 64 + ((jc ^ (rw & 7)) << 3)];
                acc[fj] = __builtin_amdgcn_mfma_f32_16x16x32_bf16(ah, wf, acc[fj], 0, 0, 0);
                acc[fj] = __builtin_amdgcn_mfma_f32_16x16x32_bf16(al, wf, acc[fj], 0, 0, 0);
            }
        }
        asm volatile("s_barrier" ::: "memory");                // reads done before overwrite
    }

    // epilogue: fused cell.  C-layout col=lane&15, row=(lane>>4)*4+r.
    const int ccol = lane & 15, crow = (lane >> 4) << 2;
#pragma unroll
    for (int h16 = 0; h16 < 2; ++h16) {
        const int hcol = (nt << 5) + (h16 << 4) + ccol;    // global h column
        const int xcol = n0 + (h16 << 4) + ccol;           // Xg col (gate i)
#pragma unroll
        for (int r = 0; r < 4; ++r) {
            const int b = rbase + (wid << 4) + crow + r;
            const float* xg = Xg + (size_t)b * NG + xcol;
            const float iv = acc[h16][r]     + xg[0];
            const float fv = acc[h16 + 2][r] + xg[32];
            const float gv = acc[h16 + 4][r] + xg[64];
            const float ov = acc[h16 + 6][r] + xg[96];
            const float cp = cprev[(size_t)b * NH + hcol];
            const float cn = sigmoidf_(fv) * cp + sigmoidf_(iv) * tanhf(gv);
            const float hn = sigmoidf_(ov) * tanhf(cn);
            cnext[(size_t)b * NH + hcol] = cn;
            const ushort hb = f2bf(hn);
            Hhi_out[(size_t)b * NH + hcol] = hb;
            Hlo_out[(size_t)b * NH + hcol] = f2bf(hn - bf2f(hb));
        }
    }
}

// ---------------------------------------------------------------------------
extern "C" void kernel_launch(void* const* d_in, const int* in_sizes, int n_in,
                              void* d_out, int out_size, void* d_ws, size_t ws_size,
                              hipStream_t stream) {
    const float* features = (const float*)d_in[0];
    const int*   captions = (const int*)d_in[1];
    const int*   lengths  = (const int*)d_in[2];
    const float* h0       = (const float*)d_in[3];
    const float* c0       = (const float*)d_in[4];
    const float* embed_w  = (const float*)d_in[5];
    const float* w_ih     = (const float*)d_in[6];
    const float* w_hh     = (const float*)d_in[7];
    const float* b_ih     = (const float*)d_in[8];
    const float* b_hh     = (const float*)d_in[9];
    const float* lin_w    = (const float*)d_in[10];
    const float* lin_b    = (const float*)d_in[11];
    float* out = (float*)d_out;

    const int M3    = out_size / NV;        // packed rows (sum of lengths)
    const int mt3   = (M3 + 127) >> 7;
    const int mpad3 = mt3 << 7;

    char* p = (char*)d_ws;
    auto alloc = [&](size_t bytes) { char* r = p; p += (bytes + 255) & ~(size_t)255; return r; };
    float*  Xgate = (float*)alloc(sizeof(float) * (size_t)NT * NB * NG);        // 21 MB
    ushort* HbfA  = (ushort*)alloc(sizeof(ushort) * (size_t)(NT + 1) * NB * NH); // 2.75 MB
    ushort* HloA  = (ushort*)alloc(sizeof(ushort) * (size_t)(NT + 1) * NB * NH); // 2.75 MB
    float*  cbuf  = (float*)alloc(sizeof(float) * (size_t)2 * NB * NH);
    float*  biasr = (float*)alloc(sizeof(float) * NG);
    int*    idx3  = (int*)alloc(sizeof(int) * (size_t)NT * NB);
    ushort* Xpack = (ushort*)alloc(sizeof(ushort) * (size_t)NT * NB * NK);      // 2.6 MB
    ushort* Apack = (ushort*)alloc(sizeof(ushort) * (size_t)mpad3 * NK);        // 1.7 MB
    ushort* Wihr  = (ushort*)alloc(sizeof(ushort) * (size_t)NG * NK);           // 2.1 MB
    ushort* Whr   = (ushort*)alloc(sizeof(ushort) * (size_t)NG * NK);           // 2.1 MB
    ushort* Wlinb = (ushort*)alloc(sizeof(ushort) * (size_t)NV * NK);           // 32.8 MB

    prep_kernel<<<1, 256, 0, stream>>>(lengths, b_ih, b_hh, biasr, idx3, mpad3);
    wconv_r_kernel<<<NG * 64 / 256, 256, 0, stream>>>(w_ih, Wihr);
    wconv_r_kernel<<<NG * 64 / 256, 256, 0, stream>>>(w_hh, Whr);
    wconv_kernel<<<(NV * NK / 8 + 255) / 256, 256, 0, stream>>>(lin_w, Wlinb, NV * NK / 8);
    xpack_kernel<<<NT * NB * 64 / 256, 256, 0, stream>>>(features, captions, embed_w, Xpack);
    split_kernel<<<NB * NH / 8 / 256, 256, 0, stream>>>(h0, c0, HbfA, HloA, cbuf);

    // Xgate[t*B+b][perm-col] = Xpack @ Wihr^T + biasr   [2560 x 2048]
    mfma_gemm_kernel<<<dim3(NT * NB / 128, NG / 128), 256, 0, stream>>>(
        Xpack, Wihr, biasr, Xgate, NG, NT * NB);

    // recurrence: 20 fused gemm+cell launches, dbuf'd + counted-vmcnt staging
    for (int t = 0; t < NT; ++t) {
        const ushort* Ahi = HbfA + (size_t)t * NB * NH;
        const ushort* Alo = HloA + (size_t)t * NB * NH;
        const float*  cpv = cbuf + (size_t)(t & 1) * NB * NH;
        float*        cnx = cbuf + (size_t)((t + 1) & 1) * NB * NH;
        rec_step2_kernel<<<32, 256, 0, stream>>>(
            Ahi, Alo, Whr, Xgate + (size_t)t * NB * NG, cpv, cnx,
            HbfA + (size_t)(t + 1) * NB * NH, HloA + (size_t)(t + 1) * NB * NH);
    }

    gather_kernel<<<mpad3 * 64 / 256, 256, 0, stream>>>(HbfA, idx3, Apack);

    // out = Apack @ Wlinb^T + lin_b   [M3 x 32000]
    mfma_gemm_kernel<<<dim3(mt3, NV / 128), 256, 0, stream>>>(
        Apack, Wlinb, lin_b, out, NV, M3);
}